// Round 1
// baseline (134.807 us; speedup 1.0000x reference)
//
#include <hip/hip_runtime.h>
#include <hip/hip_bf16.h>
#include <math.h>

typedef __hip_bfloat16 bf16;
typedef __attribute__((ext_vector_type(8))) short bf16x8;
typedef __attribute__((ext_vector_type(4))) float f32x4;

#define DI static __device__ __forceinline__

constexpr int NB = 1024;   // batch
constexpr int ND = 1024;   // latent dim (= out dim)
constexpr int NP = 16;     // parts
constexpr int BK = 32;     // GEMM K-step (one 16x16x32 MFMA K)

DI float gelu_exact(float x) {
    return 0.5f * x * (1.0f + erff(x * 0.70710678118654752f));
}

// ---------- pack x: [B,D,P] f32 -> [P][B][D] bf16 ----------
// block = one b (1024 blocks x 256 thr). lane -> (p = t&15, dgroup = t>>4).
// reads: per instr 64 lanes cover 4 full 64B lines; writes: 16B chunks that
// fill full lines across the c-loop (L2 merges).
__global__ __launch_bounds__(256) void pack_x_kernel(const float* __restrict__ x,
                                                     bf16* __restrict__ xp) {
    const int b = blockIdx.x;
    const int t = threadIdx.x;
    const int p = t & 15;
    const int dg = t >> 4;                       // 0..15
    const float* xb = x + (size_t)b * ND * NP;
    bf16* dst = xp + (size_t)p * NB * ND + (size_t)b * ND;
#pragma unroll
    for (int c = 0; c < 8; ++c) {
        const int d0 = dg * 64 + c * 8;
        alignas(16) bf16 tmp[8];
#pragma unroll
        for (int j = 0; j < 8; ++j)
            tmp[j] = __float2bfloat16(xb[(size_t)(d0 + j) * NP + p]);
        *reinterpret_cast<bf16x8*>(&dst[d0]) = *reinterpret_cast<const bf16x8*>(tmp);
    }
}

// ---------- pack W: [P][O][D] f32 -> same-layout bf16 (pure convert) ----------
__global__ __launch_bounds__(256) void pack_w_kernel(const float* __restrict__ w,
                                                     bf16* __restrict__ wp) {
    const size_t i = ((size_t)blockIdx.x * 256 + threadIdx.x) * 8;
    const float4 f0 = *reinterpret_cast<const float4*>(&w[i]);
    const float4 f1 = *reinterpret_cast<const float4*>(&w[i + 4]);
    alignas(16) bf16 tmp[8] = { __float2bfloat16(f0.x), __float2bfloat16(f0.y),
                                __float2bfloat16(f0.z), __float2bfloat16(f0.w),
                                __float2bfloat16(f1.x), __float2bfloat16(f1.y),
                                __float2bfloat16(f1.z), __float2bfloat16(f1.w) };
    *reinterpret_cast<bf16x8*>(&wp[i]) = *reinterpret_cast<const bf16x8*>(tmp);
}

// ---------- grouped GEMM, m97 structure ----------
// per part p: C[b][o] = sum_d A[b][d] * Bm[o][d]   (both K-major, "B^T input")
// 128x128 tile, 4 waves (2x2 of 64x64), BK=32, double-buffered LDS staged via
// global_load_lds width 16. DIRECT: gelu + strided store to out[b][o][p];
// else raw f32 store to y[P][B][O] (coalesced).
template<bool DIRECT>
__global__ __launch_bounds__(256, 2) void gemm_kernel(const bf16* __restrict__ xp,
                                                      const bf16* __restrict__ wp,
                                                      float* __restrict__ yout) {
    __shared__ bf16 As[2][128 * BK];
    __shared__ bf16 Bs[2][128 * BK];
    const int p  = blockIdx.z;
    const int bt = blockIdx.y * 128;
    const int ot = blockIdx.x * 128;
    const bf16* A  = xp + (size_t)p * NB * ND;   // [B][D]
    const bf16* Bm = wp + (size_t)p * ND * ND;   // [O][D]
    const int t = threadIdx.x;
    const int l = t & 63;
    const int w = t >> 6;
    const int wr = w >> 1, wc = w & 1;

    f32x4 acc[4][4] = {};

    auto stage = [&](int buf, int k0) {
#pragma unroll
        for (int r = 0; r < 2; ++r) {
            const int c   = r * 256 + t;          // chunk 0..511, 16B each
            const int row = c >> 2;
            const int cc  = c & 3;
            const bf16* ga = A  + (size_t)(bt + row) * ND + (k0 + cc * 8);
            const bf16* gb = Bm + (size_t)(ot + row) * ND + (k0 + cc * 8);
            // wave-uniform LDS base; HW writes lane i at base + i*16B
            bf16* la = &As[buf][(r * 256 + w * 64) * 8];
            bf16* lb = &Bs[buf][(r * 256 + w * 64) * 8];
            __builtin_amdgcn_global_load_lds((const __attribute__((address_space(1))) void*)ga,
                                             (__attribute__((address_space(3))) void*)la, 16, 0, 0);
            __builtin_amdgcn_global_load_lds((const __attribute__((address_space(1))) void*)gb,
                                             (__attribute__((address_space(3))) void*)lb, 16, 0, 0);
        }
    };

    int buf = 0;
    stage(0, 0);
    const int NK = ND / BK;                      // 32
    for (int kt = 0; kt < NK; ++kt) {
        __syncthreads();                          // drains vmcnt -> tile kt ready
        if (kt + 1 < NK) stage(buf ^ 1, (kt + 1) * BK);
        const int lr = l & 15;
        const int lk = (l >> 4) * 8;
        bf16x8 af[4], bf_[4];
#pragma unroll
        for (int m = 0; m < 4; ++m)
            af[m] = *reinterpret_cast<const bf16x8*>(&As[buf][(wr * 64 + m * 16 + lr) * BK + lk]);
#pragma unroll
        for (int n = 0; n < 4; ++n)
            bf_[n] = *reinterpret_cast<const bf16x8*>(&Bs[buf][(wc * 64 + n * 16 + lr) * BK + lk]);
#pragma unroll
        for (int m = 0; m < 4; ++m)
#pragma unroll
            for (int n = 0; n < 4; ++n)
                acc[m][n] = __builtin_amdgcn_mfma_f32_16x16x32_bf16(af[m], bf_[n], acc[m][n], 0, 0, 0);
        buf ^= 1;
    }

    // epilogue: C/D layout col = lane&15, row = (lane>>4)*4 + reg
    const int lr4 = (l >> 4) * 4;
    const int lc  = l & 15;
    const int row0 = bt + wr * 64, col0 = ot + wc * 64;
#pragma unroll
    for (int m = 0; m < 4; ++m) {
#pragma unroll
        for (int j = 0; j < 4; ++j) {
            const int r = row0 + m * 16 + lr4 + j;
#pragma unroll
            for (int n = 0; n < 4; ++n) {
                const int c = col0 + n * 16 + lc;
                const float v = acc[m][n][j];
                if (DIRECT) {
                    yout[((size_t)r * ND + c) * NP + p] = gelu_exact(v);
                } else {
                    yout[(size_t)p * NB * ND + (size_t)r * ND + c] = v;
                }
            }
        }
    }
}

// ---------- y [P][B][O] f32 -> out [B][O][P] f32 with exact GELU ----------
// thread = one output float4 (4 consecutive p). Reads: 4 scalar loads, lanes
// cover 64B segments per p-plane; writes: fully coalesced float4.
__global__ __launch_bounds__(256) void unpack_gelu_kernel(const float* __restrict__ y,
                                                          float* __restrict__ out) {
    const size_t f = (size_t)blockIdx.x * 256 + threadIdx.x;   // float4 index
    const int    p0 = (int)(f & 3) * 4;
    const size_t o  = (f >> 2) & 1023;
    const size_t b  = f >> 12;
    const float* yb = y + b * (size_t)ND + o;
    float4 v;
    v.x = gelu_exact(yb[(size_t)(p0 + 0) * (NB * ND)]);
    v.y = gelu_exact(yb[(size_t)(p0 + 1) * (NB * ND)]);
    v.z = gelu_exact(yb[(size_t)(p0 + 2) * (NB * ND)]);
    v.w = gelu_exact(yb[(size_t)(p0 + 3) * (NB * ND)]);
    reinterpret_cast<float4*>(out)[f] = v;
}

// ---------- insurance: pure-f32 tiled GEMM (only if ws is tiny) ----------
__global__ __launch_bounds__(256) void fallback_kernel(const float* __restrict__ x,
                                                       const float* __restrict__ w,
                                                       float* __restrict__ out) {
    __shared__ float As[64][17];
    __shared__ float Bs[64][17];
    const int p = blockIdx.z, bt = blockIdx.y * 64, ot = blockIdx.x * 64;
    const int t = threadIdx.x;
    const int tx = t & 15, ty = t >> 4;
    float acc[4][4] = {};
    for (int k0 = 0; k0 < ND; k0 += 16) {
        __syncthreads();
#pragma unroll
        for (int i = 0; i < 4; ++i) {
            const int idx = i * 256 + t;
            const int r = idx >> 4, k = idx & 15;
            As[r][k] = x[((size_t)(bt + r) * ND + k0 + k) * NP + p];
            Bs[r][k] = w[(size_t)p * ND * ND + (size_t)(ot + r) * ND + k0 + k];
        }
        __syncthreads();
#pragma unroll
        for (int k = 0; k < 16; ++k) {
            float a[4], bb[4];
#pragma unroll
            for (int i = 0; i < 4; ++i) a[i] = As[ty * 4 + i][k];
#pragma unroll
            for (int j = 0; j < 4; ++j) bb[j] = Bs[tx * 4 + j][k];
#pragma unroll
            for (int i = 0; i < 4; ++i)
#pragma unroll
                for (int j = 0; j < 4; ++j) acc[i][j] += a[i] * bb[j];
        }
    }
#pragma unroll
    for (int i = 0; i < 4; ++i)
#pragma unroll
        for (int j = 0; j < 4; ++j)
            out[((size_t)(bt + ty * 4 + i) * ND + (ot + tx * 4 + j)) * NP + p] =
                gelu_exact(acc[i][j]);
}

extern "C" void kernel_launch(void* const* d_in, const int* in_sizes, int n_in,
                              void* d_out, int out_size, void* d_ws, size_t ws_size,
                              hipStream_t stream) {
    const float* x = (const float*)d_in[0];
    const float* w = (const float*)d_in[1];
    float* out = (float*)d_out;

    const size_t nElem     = (size_t)NP * NB * ND;            // 16M
    const size_t packBytes = nElem * sizeof(bf16) * 2;        // 64 MiB (xp + wp)
    const size_t yBytes    = nElem * sizeof(float);           // 64 MiB

    if (ws_size >= packBytes) {
        bf16* xp = (bf16*)d_ws;
        bf16* wp = xp + nElem;
        pack_x_kernel<<<NB, 256, 0, stream>>>(x, xp);
        pack_w_kernel<<<(int)(nElem / (256 * 8)), 256, 0, stream>>>(w, wp);
        if (ws_size >= packBytes + yBytes) {
            float* y = (float*)((char*)d_ws + packBytes);
            gemm_kernel<false><<<dim3(8, 8, 16), 256, 0, stream>>>(xp, wp, y);
            unpack_gelu_kernel<<<(int)(nElem / (256 * 4)), 256, 0, stream>>>(y, out);
        } else {
            gemm_kernel<true><<<dim3(8, 8, 16), 256, 0, stream>>>(xp, wp, out);
        }
    } else {
        fallback_kernel<<<dim3(16, 16, 16), 256, 0, stream>>>(x, w, out);
    }
}

// Round 2
// 122.342 us; speedup vs baseline: 1.1019x; 1.1019x over previous
//
#include <hip/hip_runtime.h>
#include <hip/hip_bf16.h>
#include <math.h>

typedef __hip_bfloat16 bf16;
typedef __attribute__((ext_vector_type(8))) short bf16x8;
typedef __attribute__((ext_vector_type(4))) float f32x4;

#define DI static __device__ __forceinline__

constexpr int NB = 1024;   // batch
constexpr int ND = 1024;   // latent dim (= out dim)
constexpr int NP = 16;     // parts
constexpr int BK = 32;     // GEMM K-step (one 16x16x32 MFMA K)

DI float gelu_exact(float x) {
    return 0.5f * x * (1.0f + erff(x * 0.70710678118654752f));
}

// ---------- pack x: [B,D,P] f32 -> [P][B][D] bf16 ----------
__global__ __launch_bounds__(256) void pack_x_kernel(const float* __restrict__ x,
                                                     bf16* __restrict__ xp) {
    const int b = blockIdx.x;
    const int t = threadIdx.x;
    const int p = t & 15;
    const int dg = t >> 4;                       // 0..15
    const float* xb = x + (size_t)b * ND * NP;
    bf16* dst = xp + (size_t)p * NB * ND + (size_t)b * ND;
#pragma unroll
    for (int c = 0; c < 8; ++c) {
        const int d0 = dg * 64 + c * 8;
        alignas(16) bf16 tmp[8];
#pragma unroll
        for (int j = 0; j < 8; ++j)
            tmp[j] = __float2bfloat16(xb[(size_t)(d0 + j) * NP + p]);
        *reinterpret_cast<bf16x8*>(&dst[d0]) = *reinterpret_cast<const bf16x8*>(tmp);
    }
}

// ---------- pack W: [P][O][D] f32 -> same-layout bf16 (pure convert) ----------
__global__ __launch_bounds__(256) void pack_w_kernel(const float* __restrict__ w,
                                                     bf16* __restrict__ wp) {
    const size_t i = ((size_t)blockIdx.x * 256 + threadIdx.x) * 8;
    const float4 f0 = *reinterpret_cast<const float4*>(&w[i]);
    const float4 f1 = *reinterpret_cast<const float4*>(&w[i + 4]);
    alignas(16) bf16 tmp[8] = { __float2bfloat16(f0.x), __float2bfloat16(f0.y),
                                __float2bfloat16(f0.z), __float2bfloat16(f0.w),
                                __float2bfloat16(f1.x), __float2bfloat16(f1.y),
                                __float2bfloat16(f1.z), __float2bfloat16(f1.w) };
    *reinterpret_cast<bf16x8*>(&wp[i]) = *reinterpret_cast<const bf16x8*>(tmp);
}

// ---------- grouped GEMM, m97 structure + XCD-pinned swizzle ----------
// per part p: C[b][o] = gelu(sum_d A[b][d] * Bm[o][d])
// 128x128 tile, 4 waves (2x2 of 64x64), BK=32, double-buffered LDS via
// global_load_lds width 16. 1D grid of 1024; XCD i&7 owns parts 2*xcd,2*xcd+1
// so each part's A+W (4 MiB bf16) stays resident in that XCD's 4 MiB L2.
// YBF: gelu + bf16 store to y[P][B][O] (coalesced). DIRECT: gelu + f32
// strided store straight to out[b][o][p].
template<bool YBF>
__global__ __launch_bounds__(256, 4) void gemm_kernel(const bf16* __restrict__ xp,
                                                      const bf16* __restrict__ wp,
                                                      void* __restrict__ yout) {
    __shared__ bf16 As[2][128 * BK];
    __shared__ bf16 Bs[2][128 * BK];
    const int i = blockIdx.x;
    const int p    = ((i & 7) << 1) | ((i >> 9) & 1);   // part -> XCD i&7
    const int tile = (i >> 3) & 63;
    const int ot = (tile & 7) * 128;
    const int bt = (tile >> 3) * 128;
    const bf16* A  = xp + (size_t)p * NB * ND;   // [B][D]
    const bf16* Bm = wp + (size_t)p * ND * ND;   // [O][D]
    const int t = threadIdx.x;
    const int l = t & 63;
    const int w = t >> 6;
    const int wr = w >> 1, wc = w & 1;

    f32x4 acc[4][4] = {};

    auto stage = [&](int buf, int k0) {
#pragma unroll
        for (int r = 0; r < 2; ++r) {
            const int c   = r * 256 + t;          // chunk 0..511, 16B each
            const int row = c >> 2;
            const int cc  = c & 3;
            const bf16* ga = A  + (size_t)(bt + row) * ND + (k0 + cc * 8);
            const bf16* gb = Bm + (size_t)(ot + row) * ND + (k0 + cc * 8);
            bf16* la = &As[buf][(r * 256 + w * 64) * 8];
            bf16* lb = &Bs[buf][(r * 256 + w * 64) * 8];
            __builtin_amdgcn_global_load_lds((const __attribute__((address_space(1))) void*)ga,
                                             (__attribute__((address_space(3))) void*)la, 16, 0, 0);
            __builtin_amdgcn_global_load_lds((const __attribute__((address_space(1))) void*)gb,
                                             (__attribute__((address_space(3))) void*)lb, 16, 0, 0);
        }
    };

    int buf = 0;
    stage(0, 0);
    const int NK = ND / BK;                      // 32
    for (int kt = 0; kt < NK; ++kt) {
        __syncthreads();                          // drains vmcnt -> tile kt ready
        if (kt + 1 < NK) stage(buf ^ 1, (kt + 1) * BK);
        const int lr = l & 15;
        const int lk = (l >> 4) * 8;
        bf16x8 af[4], bf_[4];
#pragma unroll
        for (int m = 0; m < 4; ++m)
            af[m] = *reinterpret_cast<const bf16x8*>(&As[buf][(wr * 64 + m * 16 + lr) * BK + lk]);
#pragma unroll
        for (int n = 0; n < 4; ++n)
            bf_[n] = *reinterpret_cast<const bf16x8*>(&Bs[buf][(wc * 64 + n * 16 + lr) * BK + lk]);
#pragma unroll
        for (int m = 0; m < 4; ++m)
#pragma unroll
            for (int n = 0; n < 4; ++n)
                acc[m][n] = __builtin_amdgcn_mfma_f32_16x16x32_bf16(af[m], bf_[n], acc[m][n], 0, 0, 0);
        buf ^= 1;
    }

    // epilogue: C/D layout col = lane&15, row = (lane>>4)*4 + reg
    const int lr4 = (l >> 4) * 4;
    const int lc  = l & 15;
    const int row0 = bt + wr * 64, col0 = ot + wc * 64;
#pragma unroll
    for (int m = 0; m < 4; ++m) {
#pragma unroll
        for (int j = 0; j < 4; ++j) {
            const int r = row0 + m * 16 + lr4 + j;
#pragma unroll
            for (int n = 0; n < 4; ++n) {
                const int c = col0 + n * 16 + lc;
                const float v = gelu_exact(acc[m][n][j]);
                if (YBF) {
                    ((bf16*)yout)[(size_t)p * NB * ND + (size_t)r * ND + c] =
                        __float2bfloat16(v);
                } else {
                    ((float*)yout)[((size_t)r * ND + c) * NP + p] = v;
                }
            }
        }
    }
}

// ---------- y [P][B][O] bf16 (already gelu'd) -> out [B][O][P] f32 ----------
__global__ __launch_bounds__(256) void unpack_kernel(const bf16* __restrict__ y,
                                                     float* __restrict__ out) {
    const size_t f = (size_t)blockIdx.x * 256 + threadIdx.x;   // float4 index
    const int    p0 = (int)(f & 3) * 4;
    const size_t o  = (f >> 2) & 1023;
    const size_t b  = f >> 12;
    const bf16* yb = y + b * (size_t)ND + o;
    float4 v;
    v.x = __bfloat162float(yb[(size_t)(p0 + 0) * (NB * ND)]);
    v.y = __bfloat162float(yb[(size_t)(p0 + 1) * (NB * ND)]);
    v.z = __bfloat162float(yb[(size_t)(p0 + 2) * (NB * ND)]);
    v.w = __bfloat162float(yb[(size_t)(p0 + 3) * (NB * ND)]);
    reinterpret_cast<float4*>(out)[f] = v;
}

// ---------- insurance: pure-f32 tiled GEMM (only if ws is tiny) ----------
__global__ __launch_bounds__(256) void fallback_kernel(const float* __restrict__ x,
                                                       const float* __restrict__ w,
                                                       float* __restrict__ out) {
    __shared__ float As[64][17];
    __shared__ float Bs[64][17];
    const int p = blockIdx.z, bt = blockIdx.y * 64, ot = blockIdx.x * 64;
    const int t = threadIdx.x;
    const int tx = t & 15, ty = t >> 4;
    float acc[4][4] = {};
    for (int k0 = 0; k0 < ND; k0 += 16) {
        __syncthreads();
#pragma unroll
        for (int i = 0; i < 4; ++i) {
            const int idx = i * 256 + t;
            const int r = idx >> 4, k = idx & 15;
            As[r][k] = x[((size_t)(bt + r) * ND + k0 + k) * NP + p];
            Bs[r][k] = w[(size_t)p * ND * ND + (size_t)(ot + r) * ND + k0 + k];
        }
        __syncthreads();
#pragma unroll
        for (int k = 0; k < 16; ++k) {
            float a[4], bb[4];
#pragma unroll
            for (int i = 0; i < 4; ++i) a[i] = As[ty * 4 + i][k];
#pragma unroll
            for (int j = 0; j < 4; ++j) bb[j] = Bs[tx * 4 + j][k];
#pragma unroll
            for (int i = 0; i < 4; ++i)
#pragma unroll
                for (int j = 0; j < 4; ++j) acc[i][j] += a[i] * bb[j];
        }
    }
#pragma unroll
    for (int i = 0; i < 4; ++i)
#pragma unroll
        for (int j = 0; j < 4; ++j)
            out[((size_t)(bt + ty * 4 + i) * ND + (ot + tx * 4 + j)) * NP + p] =
                gelu_exact(acc[i][j]);
}

extern "C" void kernel_launch(void* const* d_in, const int* in_sizes, int n_in,
                              void* d_out, int out_size, void* d_ws, size_t ws_size,
                              hipStream_t stream) {
    const float* x = (const float*)d_in[0];
    const float* w = (const float*)d_in[1];
    float* out = (float*)d_out;

    const size_t nElem     = (size_t)NP * NB * ND;            // 16M
    const size_t packBytes = nElem * sizeof(bf16) * 2;        // 64 MiB (xp + wp)
    const size_t yBytes    = nElem * sizeof(bf16);            // 32 MiB (bf16 y)

    if (ws_size >= packBytes) {
        bf16* xp = (bf16*)d_ws;
        bf16* wp = xp + nElem;
        pack_x_kernel<<<NB, 256, 0, stream>>>(x, xp);
        pack_w_kernel<<<(int)(nElem / (256 * 8)), 256, 0, stream>>>(w, wp);
        if (ws_size >= packBytes + yBytes) {
            bf16* y = (bf16*)((char*)d_ws + packBytes);
            gemm_kernel<true><<<1024, 256, 0, stream>>>(xp, wp, y);
            unpack_kernel<<<(int)(nElem / (256 * 4)), 256, 0, stream>>>(y, out);
        } else {
            gemm_kernel<false><<<1024, 256, 0, stream>>>(xp, wp, out);
        }
    } else {
        fallback_kernel<<<dim3(16, 16, 16), 256, 0, stream>>>(x, w, out);
    }
}

// Round 3
// 119.433 us; speedup vs baseline: 1.1287x; 1.0244x over previous
//
#include <hip/hip_runtime.h>
#include <hip/hip_bf16.h>
#include <math.h>

typedef __hip_bfloat16 bf16;
typedef __attribute__((ext_vector_type(8))) short bf16x8;
typedef __attribute__((ext_vector_type(4))) float f32x4;

#define DI static __device__ __forceinline__

constexpr int NB = 1024;   // batch
constexpr int ND = 1024;   // latent dim (= out dim)
constexpr int NP = 16;     // parts
constexpr int BKT = 32;    // K-step per tile
constexpr int NKT = ND / BKT;  // 32

DI float gelu_exact(float x) {
    return 0.5f * x * (1.0f + erff(x * 0.70710678118654752f));
}

// ---------- fused pack: x [B,D,P] f32 -> xp [P][B][D] bf16 ; W f32 -> bf16 ----------
__global__ __launch_bounds__(256) void pack_kernel(const float* __restrict__ x,
                                                   const float* __restrict__ w,
                                                   bf16* __restrict__ xp,
                                                   bf16* __restrict__ wp) {
    if (blockIdx.x < NB) {
        const int b = blockIdx.x;
        const int t = threadIdx.x;
        const int p = t & 15;
        const int dg = t >> 4;
        const float* xb = x + (size_t)b * ND * NP;
        bf16* dst = xp + (size_t)p * NB * ND + (size_t)b * ND;
#pragma unroll
        for (int c = 0; c < 8; ++c) {
            const int d0 = dg * 64 + c * 8;
            alignas(16) bf16 tmp[8];
#pragma unroll
            for (int j = 0; j < 8; ++j)
                tmp[j] = __float2bfloat16(xb[(size_t)(d0 + j) * NP + p]);
            *reinterpret_cast<bf16x8*>(&dst[d0]) = *reinterpret_cast<const bf16x8*>(tmp);
        }
    } else {
        const size_t i = ((size_t)(blockIdx.x - NB) * 256 + threadIdx.x) * 8;
        const float4 f0 = *reinterpret_cast<const float4*>(&w[i]);
        const float4 f1 = *reinterpret_cast<const float4*>(&w[i + 4]);
        alignas(16) bf16 tmp[8] = { __float2bfloat16(f0.x), __float2bfloat16(f0.y),
                                    __float2bfloat16(f0.z), __float2bfloat16(f0.w),
                                    __float2bfloat16(f1.x), __float2bfloat16(f1.y),
                                    __float2bfloat16(f1.z), __float2bfloat16(f1.w) };
        *reinterpret_cast<bf16x8*>(&wp[i]) = *reinterpret_cast<const bf16x8*>(tmp);
    }
}

// ---------- grouped GEMM: 256x256 tile, 8 waves, phase-split, counted vmcnt ----------
// Per part p: y[p][b][o] = gelu_bf16( sum_d xp[p][b][d] * wp[p][o][d] )
// Triple-buffered LDS (tile kt+2 staged while computing kt, waiting on kt+1):
// steady-state wait = vmcnt(4), never 0 until the tail. T2 XOR swizzle via
// inverse-swizzled GLOBAL source + linear LDS dest (global_load_lds) +
// swizzled ds_read. 256 blocks = 1 per CU; XCD i&7 owns parts {2x, 2x+1}.
__global__ __launch_bounds__(512, 2) void gemm8_kernel(const bf16* __restrict__ xp,
                                                       const bf16* __restrict__ wp,
                                                       bf16* __restrict__ y) {
    __shared__ bf16 As[3][256 * BKT];
    __shared__ bf16 Bs[3][256 * BKT];
    const int i = blockIdx.x;
    const int p    = ((i & 7) << 1) | ((i >> 3) & 1);   // part -> XCD i&7
    const int tile = i >> 4;                             // 0..15
    const int bt = (tile >> 2) * 256;
    const int ot = (tile & 3) * 256;
    const bf16* A  = xp + (size_t)p * NB * ND;   // [B][D]
    const bf16* Bm = wp + (size_t)p * ND * ND;   // [O][D]
    const int t = threadIdx.x;
    const int l = t & 63, w = t >> 6;            // 8 waves
    const int wr = w >> 2, wc = w & 3;           // 2(M) x 4(N)
    const int lr = l & 15, g = l >> 4;           // frag row / k-chunk

    f32x4 acc[8][4] = {};

    // stage round q (0,1 = A rows; 2,3 = B rows) of K-tile kt into buffer buf.
    // LDS dest is linear (wave-uniform base + lane*16B); the XOR swizzle is
    // applied to the GLOBAL source k-chunk (rule 21: both-sides-or-neither).
    auto stage = [&](int buf, int kt, int q) {
        const int s   = ((q & 1) * 8 + w) * 64 + l;     // 16B slot 0..1023
        const int row = s >> 2;                          // 0..255
        const int cb  = (s & 3) ^ (row & 3);             // inverse-swizzled chunk
        const bf16* gsrc = (q < 2 ? A + (size_t)(bt + row) * ND
                                  : Bm + (size_t)(ot + row) * ND) + kt * BKT + cb * 8;
        bf16* ldst = (q < 2 ? &As[buf][((q & 1) * 8 + w) * 512]
                            : &Bs[buf][((q & 1) * 8 + w) * 512]);
        __builtin_amdgcn_global_load_lds((const __attribute__((address_space(1))) void*)gsrc,
                                         (__attribute__((address_space(3))) void*)ldst, 16, 0, 0);
    };
    auto readA = [&](int buf, int m) -> bf16x8 {
        const int row  = wr * 128 + m * 16 + lr;
        const int slot = row * 4 + (g ^ (row & 3));      // swizzled read
        return *reinterpret_cast<const bf16x8*>(&As[buf][slot * 8]);
    };
    auto readB = [&](int buf, int n) -> bf16x8 {
        const int row  = wc * 64 + n * 16 + lr;
        const int slot = row * 4 + (g ^ (row & 3));
        return *reinterpret_cast<const bf16x8*>(&Bs[buf][slot * 8]);
    };

    // prologue: stage tiles 0 and 1; wait for tile 0 only (tile 1 stays in flight)
#pragma unroll
    for (int q = 0; q < 4; ++q) stage(0, 0, q);
#pragma unroll
    for (int q = 0; q < 4; ++q) stage(1, 1, q);
    asm volatile("s_waitcnt vmcnt(4)" ::: "memory");
    __builtin_amdgcn_s_barrier();
    __builtin_amdgcn_sched_barrier(0);

    int bufc = 0, bufs = 2;
#pragma unroll 1
    for (int kt = 0; kt < NKT; ++kt) {
        // ---- phase 0: B frags + A frags m0..3 ; stage A of tile kt+2 ----
        bf16x8 bfr[4], af[4];
#pragma unroll
        for (int n = 0; n < 4; ++n) bfr[n] = readB(bufc, n);
#pragma unroll
        for (int m = 0; m < 4; ++m) af[m] = readA(bufc, m);
        if (kt + 2 < NKT) { stage(bufs, kt + 2, 0); stage(bufs, kt + 2, 1); }
        __builtin_amdgcn_s_barrier();
        asm volatile("s_waitcnt lgkmcnt(0)" ::: "memory");
        __builtin_amdgcn_s_setprio(1);
#pragma unroll
        for (int m = 0; m < 4; ++m)
#pragma unroll
            for (int n = 0; n < 4; ++n)
                acc[m][n] = __builtin_amdgcn_mfma_f32_16x16x32_bf16(af[m], bfr[n], acc[m][n], 0, 0, 0);
        __builtin_amdgcn_s_setprio(0);
        __builtin_amdgcn_s_barrier();
        // ---- phase 1: A frags m4..7 ; stage B of tile kt+2 ----
#pragma unroll
        for (int m = 0; m < 4; ++m) af[m] = readA(bufc, 4 + m);
        if (kt + 2 < NKT) { stage(bufs, kt + 2, 2); stage(bufs, kt + 2, 3); }
        __builtin_amdgcn_s_barrier();
        asm volatile("s_waitcnt lgkmcnt(0)" ::: "memory");
        __builtin_amdgcn_s_setprio(1);
#pragma unroll
        for (int m = 0; m < 4; ++m)
#pragma unroll
            for (int n = 0; n < 4; ++n)
                acc[4 + m][n] = __builtin_amdgcn_mfma_f32_16x16x32_bf16(af[m], bfr[n], acc[4 + m][n], 0, 0, 0);
        __builtin_amdgcn_s_setprio(0);
        // ---- iter boundary: ensure tile kt+1 resident before next iter reads it.
        // outstanding beyond tile kt+1 = tile kt+2's 4 loads (if staged) -> counted.
        if (kt < NKT - 1) {
            if (kt + 2 < NKT) asm volatile("s_waitcnt vmcnt(4)" ::: "memory");
            else              asm volatile("s_waitcnt vmcnt(0)" ::: "memory");
            __builtin_amdgcn_s_barrier();
            __builtin_amdgcn_sched_barrier(0);
        }
        bufc = (bufc == 2) ? 0 : bufc + 1;
        bufs = (bufs == 2) ? 0 : bufs + 1;
    }

    // epilogue: C/D layout col = lane&15, row = (lane>>4)*4 + j
    const int r4 = (l >> 4) * 4, lc = l & 15;
    bf16* yp = y + (size_t)p * NB * ND;
#pragma unroll
    for (int m = 0; m < 8; ++m) {
#pragma unroll
        for (int j = 0; j < 4; ++j) {
            const int row = bt + wr * 128 + m * 16 + r4 + j;
#pragma unroll
            for (int n = 0; n < 4; ++n) {
                const int col = ot + wc * 64 + n * 16 + lc;
                yp[(size_t)row * ND + col] = __float2bfloat16(gelu_exact(acc[m][n][j]));
            }
        }
    }
}

// ---------- y [P][B][O] bf16 (already gelu'd) -> out [B][O][P] f32 ----------
__global__ __launch_bounds__(256) void unpack_kernel(const bf16* __restrict__ y,
                                                     float* __restrict__ out) {
    const size_t f = (size_t)blockIdx.x * 256 + threadIdx.x;   // float4 index
    const int    p0 = (int)(f & 3) * 4;
    const size_t o  = (f >> 2) & 1023;
    const size_t b  = f >> 12;
    const bf16* yb = y + b * (size_t)ND + o;
    float4 v;
    v.x = __bfloat162float(yb[(size_t)(p0 + 0) * (NB * ND)]);
    v.y = __bfloat162float(yb[(size_t)(p0 + 1) * (NB * ND)]);
    v.z = __bfloat162float(yb[(size_t)(p0 + 2) * (NB * ND)]);
    v.w = __bfloat162float(yb[(size_t)(p0 + 3) * (NB * ND)]);
    reinterpret_cast<float4*>(out)[f] = v;
}

// ---------- fallback A: 128^2 m97-style GEMM, direct strided f32 store ----------
__global__ __launch_bounds__(256, 4) void gemm_direct_kernel(const bf16* __restrict__ xp,
                                                             const bf16* __restrict__ wp,
                                                             float* __restrict__ out) {
    constexpr int BK = 32;
    __shared__ bf16 As[2][128 * BK];
    __shared__ bf16 Bs[2][128 * BK];
    const int i = blockIdx.x;
    const int p    = ((i & 7) << 1) | ((i >> 9) & 1);
    const int tile = (i >> 3) & 63;
    const int ot = (tile & 7) * 128;
    const int bt = (tile >> 3) * 128;
    const bf16* A  = xp + (size_t)p * NB * ND;
    const bf16* Bm = wp + (size_t)p * ND * ND;
    const int t = threadIdx.x;
    const int l = t & 63;
    const int w = t >> 6;
    const int wr = w >> 1, wc = w & 1;
    f32x4 acc[4][4] = {};
    auto stage = [&](int buf, int k0) {
#pragma unroll
        for (int r = 0; r < 2; ++r) {
            const int c   = r * 256 + t;
            const int row = c >> 2;
            const int cc  = c & 3;
            const bf16* ga = A  + (size_t)(bt + row) * ND + (k0 + cc * 8);
            const bf16* gb = Bm + (size_t)(ot + row) * ND + (k0 + cc * 8);
            bf16* la = &As[buf][(r * 256 + w * 64) * 8];
            bf16* lb = &Bs[buf][(r * 256 + w * 64) * 8];
            __builtin_amdgcn_global_load_lds((const __attribute__((address_space(1))) void*)ga,
                                             (__attribute__((address_space(3))) void*)la, 16, 0, 0);
            __builtin_amdgcn_global_load_lds((const __attribute__((address_space(1))) void*)gb,
                                             (__attribute__((address_space(3))) void*)lb, 16, 0, 0);
        }
    };
    int buf = 0;
    stage(0, 0);
    for (int kt = 0; kt < ND / BK; ++kt) {
        __syncthreads();
        if (kt + 1 < ND / BK) stage(buf ^ 1, (kt + 1) * BK);
        const int lr = l & 15;
        const int lk = (l >> 4) * 8;
        bf16x8 af[4], bfr[4];
#pragma unroll
        for (int m = 0; m < 4; ++m)
            af[m] = *reinterpret_cast<const bf16x8*>(&As[buf][(wr * 64 + m * 16 + lr) * BK + lk]);
#pragma unroll
        for (int n = 0; n < 4; ++n)
            bfr[n] = *reinterpret_cast<const bf16x8*>(&Bs[buf][(wc * 64 + n * 16 + lr) * BK + lk]);
#pragma unroll
        for (int m = 0; m < 4; ++m)
#pragma unroll
            for (int n = 0; n < 4; ++n)
                acc[m][n] = __builtin_amdgcn_mfma_f32_16x16x32_bf16(af[m], bfr[n], acc[m][n], 0, 0, 0);
        buf ^= 1;
    }
    const int lr4 = (l >> 4) * 4;
    const int lc  = l & 15;
    const int row0 = bt + wr * 64, col0 = ot + wc * 64;
#pragma unroll
    for (int m = 0; m < 4; ++m)
#pragma unroll
        for (int j = 0; j < 4; ++j) {
            const int r = row0 + m * 16 + lr4 + j;
#pragma unroll
            for (int n = 0; n < 4; ++n) {
                const int c = col0 + n * 16 + lc;
                out[((size_t)r * ND + c) * NP + p] = gelu_exact(acc[m][n][j]);
            }
        }
}

// ---------- fallback B: pure-f32 tiled GEMM (tiny ws) ----------
__global__ __launch_bounds__(256) void fallback_kernel(const float* __restrict__ x,
                                                       const float* __restrict__ w,
                                                       float* __restrict__ out) {
    __shared__ float As[64][17];
    __shared__ float Bs[64][17];
    const int p = blockIdx.z, bt = blockIdx.y * 64, ot = blockIdx.x * 64;
    const int t = threadIdx.x;
    const int tx = t & 15, ty = t >> 4;
    float acc[4][4] = {};
    for (int k0 = 0; k0 < ND; k0 += 16) {
        __syncthreads();
#pragma unroll
        for (int i = 0; i < 4; ++i) {
            const int idx = i * 256 + t;
            const int r = idx >> 4, k = idx & 15;
            As[r][k] = x[((size_t)(bt + r) * ND + k0 + k) * NP + p];
            Bs[r][k] = w[(size_t)p * ND * ND + (size_t)(ot + r) * ND + k0 + k];
        }
        __syncthreads();
#pragma unroll
        for (int k = 0; k < 16; ++k) {
            float a[4], bb[4];
#pragma unroll
            for (int i = 0; i < 4; ++i) a[i] = As[ty * 4 + i][k];
#pragma unroll
            for (int j = 0; j < 4; ++j) bb[j] = Bs[tx * 4 + j][k];
#pragma unroll
            for (int i = 0; i < 4; ++i)
#pragma unroll
                for (int j = 0; j < 4; ++j) acc[i][j] += a[i] * bb[j];
        }
    }
#pragma unroll
    for (int i = 0; i < 4; ++i)
#pragma unroll
        for (int j = 0; j < 4; ++j)
            out[((size_t)(bt + ty * 4 + i) * ND + (ot + tx * 4 + j)) * NP + p] =
                gelu_exact(acc[i][j]);
}

extern "C" void kernel_launch(void* const* d_in, const int* in_sizes, int n_in,
                              void* d_out, int out_size, void* d_ws, size_t ws_size,
                              hipStream_t stream) {
    const float* x = (const float*)d_in[0];
    const float* w = (const float*)d_in[1];
    float* out = (float*)d_out;

    const size_t nElem     = (size_t)NP * NB * ND;            // 16M
    const size_t packBytes = nElem * sizeof(bf16) * 2;        // 64 MiB (xp + wp)
    const size_t yBytes    = nElem * sizeof(bf16);            // 32 MiB (bf16 y)

    if (ws_size >= packBytes) {
        bf16* xp = (bf16*)d_ws;
        bf16* wp = xp + nElem;
        pack_kernel<<<NB + (int)(nElem / (256 * 8)), 256, 0, stream>>>(x, w, xp, wp);
        if (ws_size >= packBytes + yBytes) {
            bf16* y = (bf16*)((char*)d_ws + packBytes);
            gemm8_kernel<<<256, 512, 0, stream>>>(xp, wp, y);
            unpack_kernel<<<(int)(nElem / (256 * 4)), 256, 0, stream>>>(y, out);
        } else {
            gemm_direct_kernel<<<1024, 256, 0, stream>>>(xp, wp, out);
        }
    } else {
        fallback_kernel<<<dim3(16, 16, 16), 256, 0, stream>>>(x, w, out);
    }
}

// Round 4
// 114.688 us; speedup vs baseline: 1.1754x; 1.0414x over previous
//
#include <hip/hip_runtime.h>
#include <hip/hip_bf16.h>
#include <math.h>

typedef __hip_bfloat16 bf16;
typedef __attribute__((ext_vector_type(8))) short bf16x8;
typedef __attribute__((ext_vector_type(4))) float f32x4;

#define DI static __device__ __forceinline__

constexpr int NB = 1024;   // batch
constexpr int ND = 1024;   // latent dim (= out dim)
constexpr int NP = 16;     // parts
constexpr int BKT = 32;    // K-step per tile
constexpr int NKT = ND / BKT;  // 32
constexpr int LDP = 1032;  // LDS row stride (bf16): 516 words -> 2-way banks (free)

DI float gelu_exact(float x) {
    return 0.5f * x * (1.0f + erff(x * 0.70710678118654752f));
}

DI ushort bf16_bits(float f) {
    bf16 h = __float2bfloat16(f);
    return *reinterpret_cast<ushort*>(&h);
}

// ---------- fused pack ----------
// blocks [0, NB): x [B,D,P] f32 -> xp [P][B][D] bf16 via LDS transpose.
// blocks [NB, ...): W [P][O][D] f32 -> wp bf16 (pure vectorized convert).
__global__ __launch_bounds__(256) void pack_kernel(const float* __restrict__ x,
                                                   const float* __restrict__ w,
                                                   bf16* __restrict__ xp,
                                                   bf16* __restrict__ wp) {
    __shared__ ushort lds[16][LDP];
    if (blockIdx.x < NB) {
        const int b = blockIdx.x;
        const int t = threadIdx.x;
        const float* xb = x + (size_t)b * (ND * NP);
        // phase 1: coalesced float4 loads, pack (d,d+1) bf16 pairs into 4B words
#pragma unroll
        for (int it = 0; it < 8; ++it) {
            const int u  = it * 256 + t;        // 0..2047
            const int dh = u >> 2;              // d pair index 0..511
            const int p0 = (u & 3) * 4;
            const float4 va = *reinterpret_cast<const float4*>(&xb[(size_t)(dh * 2)     * NP + p0]);
            const float4 vb = *reinterpret_cast<const float4*>(&xb[(size_t)(dh * 2 + 1) * NP + p0]);
            const float a0[4] = { va.x, va.y, va.z, va.w };
            const float a1[4] = { vb.x, vb.y, vb.z, vb.w };
#pragma unroll
            for (int k = 0; k < 4; ++k) {
                const uint packed = (uint)bf16_bits(a0[k]) | ((uint)bf16_bits(a1[k]) << 16);
                *reinterpret_cast<uint*>(&lds[p0 + k][dh * 2]) = packed;
            }
        }
        __syncthreads();
        // phase 2: per-p contiguous bf16x8 reads -> coalesced global stores
        const int p = threadIdx.x >> 4, j = threadIdx.x & 15;
        bf16* dst = xp + (size_t)p * (NB * ND) + (size_t)b * ND;
#pragma unroll
        for (int it = 0; it < 8; ++it) {
            const int c = it * 16 + j;          // 0..127 chunks of 8 bf16
            *reinterpret_cast<bf16x8*>(&dst[c * 8]) =
                *reinterpret_cast<const bf16x8*>(&lds[p][c * 8]);
        }
    } else {
        const size_t i = ((size_t)(blockIdx.x - NB) * 256 + threadIdx.x) * 8;
        const float4 f0 = *reinterpret_cast<const float4*>(&w[i]);
        const float4 f1 = *reinterpret_cast<const float4*>(&w[i + 4]);
        alignas(16) bf16 tmp[8] = { __float2bfloat16(f0.x), __float2bfloat16(f0.y),
                                    __float2bfloat16(f0.z), __float2bfloat16(f0.w),
                                    __float2bfloat16(f1.x), __float2bfloat16(f1.y),
                                    __float2bfloat16(f1.z), __float2bfloat16(f1.w) };
        *reinterpret_cast<bf16x8*>(&wp[i]) = *reinterpret_cast<const bf16x8*>(tmp);
    }
}

// ---------- grouped GEMM: 256x256 tile, 8 waves, phase-split, counted vmcnt ----------
// Per part p: y[p][b][o] = gelu_bf16( sum_d xp[p][b][d] * wp[p][o][d] )
// Triple-buffered LDS; steady-state wait = vmcnt(4), never 0 until the tail.
// T2 XOR swizzle via inverse-swizzled GLOBAL source + linear LDS dest +
// swizzled ds_read. 256 blocks = 1 per CU; XCD i&7 owns parts {2x, 2x+1}.
__global__ __launch_bounds__(512, 2) void gemm8_kernel(const bf16* __restrict__ xp,
                                                       const bf16* __restrict__ wp,
                                                       bf16* __restrict__ y) {
    __shared__ bf16 As[3][256 * BKT];
    __shared__ bf16 Bs[3][256 * BKT];
    const int i = blockIdx.x;
    const int p    = ((i & 7) << 1) | ((i >> 3) & 1);   // part -> XCD i&7
    const int tile = i >> 4;                             // 0..15
    const int bt = (tile >> 2) * 256;
    const int ot = (tile & 3) * 256;
    const bf16* A  = xp + (size_t)p * NB * ND;   // [B][D]
    const bf16* Bm = wp + (size_t)p * ND * ND;   // [O][D]
    const int t = threadIdx.x;
    const int l = t & 63, w = t >> 6;            // 8 waves
    const int wr = w >> 2, wc = w & 3;           // 2(M) x 4(N)
    const int lr = l & 15, g = l >> 4;           // frag row / k-chunk

    f32x4 acc[8][4] = {};

    auto stage = [&](int buf, int kt, int q) {
        const int s   = ((q & 1) * 8 + w) * 64 + l;     // 16B slot 0..1023
        const int row = s >> 2;                          // 0..255
        const int cb  = (s & 3) ^ (row & 3);             // inverse-swizzled chunk
        const bf16* gsrc = (q < 2 ? A + (size_t)(bt + row) * ND
                                  : Bm + (size_t)(ot + row) * ND) + kt * BKT + cb * 8;
        bf16* ldst = (q < 2 ? &As[buf][((q & 1) * 8 + w) * 512]
                            : &Bs[buf][((q & 1) * 8 + w) * 512]);
        __builtin_amdgcn_global_load_lds((const __attribute__((address_space(1))) void*)gsrc,
                                         (__attribute__((address_space(3))) void*)ldst, 16, 0, 0);
    };
    auto readA = [&](int buf, int m) -> bf16x8 {
        const int row  = wr * 128 + m * 16 + lr;
        const int slot = row * 4 + (g ^ (row & 3));      // swizzled read
        return *reinterpret_cast<const bf16x8*>(&As[buf][slot * 8]);
    };
    auto readB = [&](int buf, int n) -> bf16x8 {
        const int row  = wc * 64 + n * 16 + lr;
        const int slot = row * 4 + (g ^ (row & 3));
        return *reinterpret_cast<const bf16x8*>(&Bs[buf][slot * 8]);
    };

#pragma unroll
    for (int q = 0; q < 4; ++q) stage(0, 0, q);
#pragma unroll
    for (int q = 0; q < 4; ++q) stage(1, 1, q);
    asm volatile("s_waitcnt vmcnt(4)" ::: "memory");
    __builtin_amdgcn_s_barrier();
    __builtin_amdgcn_sched_barrier(0);

    int bufc = 0, bufs = 2;
#pragma unroll 1
    for (int kt = 0; kt < NKT; ++kt) {
        // ---- phase 0: B frags + A frags m0..3 ; stage A of tile kt+2 ----
        bf16x8 bfr[4], af[4];
#pragma unroll
        for (int n = 0; n < 4; ++n) bfr[n] = readB(bufc, n);
#pragma unroll
        for (int m = 0; m < 4; ++m) af[m] = readA(bufc, m);
        if (kt + 2 < NKT) { stage(bufs, kt + 2, 0); stage(bufs, kt + 2, 1); }
        __builtin_amdgcn_s_barrier();
        asm volatile("s_waitcnt lgkmcnt(0)" ::: "memory");
        __builtin_amdgcn_s_setprio(1);
#pragma unroll
        for (int m = 0; m < 4; ++m)
#pragma unroll
            for (int n = 0; n < 4; ++n)
                acc[m][n] = __builtin_amdgcn_mfma_f32_16x16x32_bf16(af[m], bfr[n], acc[m][n], 0, 0, 0);
        __builtin_amdgcn_s_setprio(0);
        __builtin_amdgcn_s_barrier();
        // ---- phase 1: A frags m4..7 ; stage B of tile kt+2 ----
#pragma unroll
        for (int m = 0; m < 4; ++m) af[m] = readA(bufc, 4 + m);
        if (kt + 2 < NKT) { stage(bufs, kt + 2, 2); stage(bufs, kt + 2, 3); }
        __builtin_amdgcn_s_barrier();
        asm volatile("s_waitcnt lgkmcnt(0)" ::: "memory");
        __builtin_amdgcn_s_setprio(1);
#pragma unroll
        for (int m = 0; m < 4; ++m)
#pragma unroll
            for (int n = 0; n < 4; ++n)
                acc[4 + m][n] = __builtin_amdgcn_mfma_f32_16x16x32_bf16(af[m], bfr[n], acc[4 + m][n], 0, 0, 0);
        __builtin_amdgcn_s_setprio(0);
        if (kt < NKT - 1) {
            if (kt + 2 < NKT) asm volatile("s_waitcnt vmcnt(4)" ::: "memory");
            else              asm volatile("s_waitcnt vmcnt(0)" ::: "memory");
            __builtin_amdgcn_s_barrier();
            __builtin_amdgcn_sched_barrier(0);
        }
        bufc = (bufc == 2) ? 0 : bufc + 1;
        bufs = (bufs == 2) ? 0 : bufs + 1;
    }

    const int r4 = (l >> 4) * 4, lc = l & 15;
    bf16* yp = y + (size_t)p * NB * ND;
#pragma unroll
    for (int m = 0; m < 8; ++m) {
#pragma unroll
        for (int j = 0; j < 4; ++j) {
            const int row = bt + wr * 128 + m * 16 + r4 + j;
#pragma unroll
            for (int n = 0; n < 4; ++n) {
                const int col = ot + wc * 64 + n * 16 + lc;
                yp[(size_t)row * ND + col] = __float2bfloat16(gelu_exact(acc[m][n][j]));
            }
        }
    }
}

// ---------- y [P][B][O] bf16 (already gelu'd) -> out [B][O][P] f32 ----------
// thread = one (b,o): 16 plane loads, each 128B-contiguous across the wave;
// writes 4x float4 = 16KB contiguous per wave.
__global__ __launch_bounds__(256) void unpack_kernel(const bf16* __restrict__ y,
                                                     float* __restrict__ out) {
    const size_t gidx = (size_t)blockIdx.x * 256 + threadIdx.x;  // (b,o) index
    const size_t o = gidx & 1023;
    const size_t b = gidx >> 10;
    const bf16* yb = y + b * (size_t)ND + o;
    float v[16];
#pragma unroll
    for (int p = 0; p < 16; ++p)
        v[p] = __bfloat162float(yb[(size_t)p * (NB * ND)]);
    float4* dst = reinterpret_cast<float4*>(out + gidx * NP);
#pragma unroll
    for (int q = 0; q < 4; ++q)
        dst[q] = make_float4(v[q * 4], v[q * 4 + 1], v[q * 4 + 2], v[q * 4 + 3]);
}

// ---------- fallback A: 128^2 m97-style GEMM, direct strided f32 store ----------
__global__ __launch_bounds__(256, 4) void gemm_direct_kernel(const bf16* __restrict__ xp,
                                                             const bf16* __restrict__ wp,
                                                             float* __restrict__ out) {
    constexpr int BK = 32;
    __shared__ bf16 As[2][128 * BK];
    __shared__ bf16 Bs[2][128 * BK];
    const int i = blockIdx.x;
    const int p    = ((i & 7) << 1) | ((i >> 9) & 1);
    const int tile = (i >> 3) & 63;
    const int ot = (tile & 7) * 128;
    const int bt = (tile >> 3) * 128;
    const bf16* A  = xp + (size_t)p * NB * ND;
    const bf16* Bm = wp + (size_t)p * ND * ND;
    const int t = threadIdx.x;
    const int l = t & 63;
    const int w = t >> 6;
    const int wr = w >> 1, wc = w & 1;
    f32x4 acc[4][4] = {};
    auto stage = [&](int buf, int k0) {
#pragma unroll
        for (int r = 0; r < 2; ++r) {
            const int c   = r * 256 + t;
            const int row = c >> 2;
            const int cc  = c & 3;
            const bf16* ga = A  + (size_t)(bt + row) * ND + (k0 + cc * 8);
            const bf16* gb = Bm + (size_t)(ot + row) * ND + (k0 + cc * 8);
            bf16* la = &As[buf][(r * 256 + w * 64) * 8];
            bf16* lb = &Bs[buf][(r * 256 + w * 64) * 8];
            __builtin_amdgcn_global_load_lds((const __attribute__((address_space(1))) void*)ga,
                                             (__attribute__((address_space(3))) void*)la, 16, 0, 0);
            __builtin_amdgcn_global_load_lds((const __attribute__((address_space(1))) void*)gb,
                                             (__attribute__((address_space(3))) void*)lb, 16, 0, 0);
        }
    };
    int buf = 0;
    stage(0, 0);
    for (int kt = 0; kt < ND / BK; ++kt) {
        __syncthreads();
        if (kt + 1 < ND / BK) stage(buf ^ 1, (kt + 1) * BK);
        const int lr = l & 15;
        const int lk = (l >> 4) * 8;
        bf16x8 af[4], bfr[4];
#pragma unroll
        for (int m = 0; m < 4; ++m)
            af[m] = *reinterpret_cast<const bf16x8*>(&As[buf][(wr * 64 + m * 16 + lr) * BK + lk]);
#pragma unroll
        for (int n = 0; n < 4; ++n)
            bfr[n] = *reinterpret_cast<const bf16x8*>(&Bs[buf][(wc * 64 + n * 16 + lr) * BK + lk]);
#pragma unroll
        for (int m = 0; m < 4; ++m)
#pragma unroll
            for (int n = 0; n < 4; ++n)
                acc[m][n] = __builtin_amdgcn_mfma_f32_16x16x32_bf16(af[m], bfr[n], acc[m][n], 0, 0, 0);
        buf ^= 1;
    }
    const int lr4 = (l >> 4) * 4;
    const int lc  = l & 15;
    const int row0 = bt + wr * 64, col0 = ot + wc * 64;
#pragma unroll
    for (int m = 0; m < 4; ++m)
#pragma unroll
        for (int j = 0; j < 4; ++j) {
            const int r = row0 + m * 16 + lr4 + j;
#pragma unroll
            for (int n = 0; n < 4; ++n) {
                const int c = col0 + n * 16 + lc;
                out[((size_t)r * ND + c) * NP + p] = gelu_exact(acc[m][n][j]);
            }
        }
}

// ---------- fallback B: pure-f32 tiled GEMM (tiny ws) ----------
__global__ __launch_bounds__(256) void fallback_kernel(const float* __restrict__ x,
                                                       const float* __restrict__ w,
                                                       float* __restrict__ out) {
    __shared__ float As[64][17];
    __shared__ float Bs[64][17];
    const int p = blockIdx.z, bt = blockIdx.y * 64, ot = blockIdx.x * 64;
    const int t = threadIdx.x;
    const int tx = t & 15, ty = t >> 4;
    float acc[4][4] = {};
    for (int k0 = 0; k0 < ND; k0 += 16) {
        __syncthreads();
#pragma unroll
        for (int i = 0; i < 4; ++i) {
            const int idx = i * 256 + t;
            const int r = idx >> 4, k = idx & 15;
            As[r][k] = x[((size_t)(bt + r) * ND + k0 + k) * NP + p];
            Bs[r][k] = w[(size_t)p * ND * ND + (size_t)(ot + r) * ND + k0 + k];
        }
        __syncthreads();
#pragma unroll
        for (int k = 0; k < 16; ++k) {
            float a[4], bb[4];
#pragma unroll
            for (int i = 0; i < 4; ++i) a[i] = As[ty * 4 + i][k];
#pragma unroll
            for (int j = 0; j < 4; ++j) bb[j] = Bs[tx * 4 + j][k];
#pragma unroll
            for (int i = 0; i < 4; ++i)
#pragma unroll
                for (int j = 0; j < 4; ++j) acc[i][j] += a[i] * bb[j];
        }
    }
#pragma unroll
    for (int i = 0; i < 4; ++i)
#pragma unroll
        for (int j = 0; j < 4; ++j)
            out[((size_t)(bt + ty * 4 + i) * ND + (ot + tx * 4 + j)) * NP + p] =
                gelu_exact(acc[i][j]);
}

extern "C" void kernel_launch(void* const* d_in, const int* in_sizes, int n_in,
                              void* d_out, int out_size, void* d_ws, size_t ws_size,
                              hipStream_t stream) {
    const float* x = (const float*)d_in[0];
    const float* w = (const float*)d_in[1];
    float* out = (float*)d_out;

    const size_t nElem     = (size_t)NP * NB * ND;            // 16M
    const size_t packBytes = nElem * sizeof(bf16) * 2;        // 64 MiB (xp + wp)
    const size_t yBytes    = nElem * sizeof(bf16);            // 32 MiB (bf16 y)

    if (ws_size >= packBytes) {
        bf16* xp = (bf16*)d_ws;
        bf16* wp = xp + nElem;
        pack_kernel<<<NB + (int)(nElem / (256 * 8)), 256, 0, stream>>>(x, w, xp, wp);
        if (ws_size >= packBytes + yBytes) {
            bf16* y = (bf16*)((char*)d_ws + packBytes);
            gemm8_kernel<<<256, 512, 0, stream>>>(xp, wp, y);
            unpack_kernel<<<(int)(NB * ND / 256), 256, 0, stream>>>(y, out);
        } else {
            gemm_direct_kernel<<<1024, 256, 0, stream>>>(xp, wp, out);
        }
    } else {
        fallback_kernel<<<dim3(16, 16, 16), 256, 0, stream>>>(x, w, out);
    }
}

// Round 5
// 110.572 us; speedup vs baseline: 1.2192x; 1.0372x over previous
//
#include <hip/hip_runtime.h>
#include <hip/hip_bf16.h>
#include <math.h>

typedef __hip_bfloat16 bf16;
typedef __attribute__((ext_vector_type(8))) short bf16x8;
typedef __attribute__((ext_vector_type(4))) float f32x4;
typedef __attribute__((ext_vector_type(16))) float f32x16;

#define DI static __device__ __forceinline__

constexpr int NB = 1024;   // batch
constexpr int ND = 1024;   // latent dim (= out dim)
constexpr int NP = 16;     // parts
constexpr int BKT = 32;    // K-step per tile
constexpr int NKT = ND / BKT;  // 32
constexpr int LDP = 1032;  // LDS row stride (bf16) for pack transpose

DI float gelu_exact(float x) {
    return 0.5f * x * (1.0f + erff(x * 0.70710678118654752f));
}

DI ushort bf16_bits(float f) {
    bf16 h = __float2bfloat16(f);
    return *reinterpret_cast<ushort*>(&h);
}

// ---------- fused pack ----------
// blocks [0, NB): x [B,D,P] f32 -> xp [P][B][D] bf16 via LDS transpose.
// blocks [NB, ...): W [P][O][D] f32 -> wp bf16 (pure vectorized convert).
__global__ __launch_bounds__(256) void pack_kernel(const float* __restrict__ x,
                                                   const float* __restrict__ w,
                                                   bf16* __restrict__ xp,
                                                   bf16* __restrict__ wp) {
    __shared__ ushort lds[16][LDP];
    if (blockIdx.x < NB) {
        const int b = blockIdx.x;
        const int t = threadIdx.x;
        const float* xb = x + (size_t)b * (ND * NP);
#pragma unroll
        for (int it = 0; it < 8; ++it) {
            const int u  = it * 256 + t;        // 0..2047
            const int dh = u >> 2;              // d pair index 0..511
            const int p0 = (u & 3) * 4;
            const float4 va = *reinterpret_cast<const float4*>(&xb[(size_t)(dh * 2)     * NP + p0]);
            const float4 vb = *reinterpret_cast<const float4*>(&xb[(size_t)(dh * 2 + 1) * NP + p0]);
            const float a0[4] = { va.x, va.y, va.z, va.w };
            const float a1[4] = { vb.x, vb.y, vb.z, vb.w };
#pragma unroll
            for (int k = 0; k < 4; ++k) {
                const uint packed = (uint)bf16_bits(a0[k]) | ((uint)bf16_bits(a1[k]) << 16);
                *reinterpret_cast<uint*>(&lds[p0 + k][dh * 2]) = packed;
            }
        }
        __syncthreads();
        const int p = threadIdx.x >> 4, j = threadIdx.x & 15;
        bf16* dst = xp + (size_t)p * (NB * ND) + (size_t)b * ND;
#pragma unroll
        for (int it = 0; it < 8; ++it) {
            const int c = it * 16 + j;          // 0..127 chunks of 8 bf16
            *reinterpret_cast<bf16x8*>(&dst[c * 8]) =
                *reinterpret_cast<const bf16x8*>(&lds[p][c * 8]);
        }
    } else {
        const size_t i = ((size_t)(blockIdx.x - NB) * 256 + threadIdx.x) * 8;
        const float4 f0 = *reinterpret_cast<const float4*>(&w[i]);
        const float4 f1 = *reinterpret_cast<const float4*>(&w[i + 4]);
        alignas(16) bf16 tmp[8] = { __float2bfloat16(f0.x), __float2bfloat16(f0.y),
                                    __float2bfloat16(f0.z), __float2bfloat16(f0.w),
                                    __float2bfloat16(f1.x), __float2bfloat16(f1.y),
                                    __float2bfloat16(f1.z), __float2bfloat16(f1.w) };
        *reinterpret_cast<bf16x8*>(&wp[i]) = *reinterpret_cast<const bf16x8*>(tmp);
    }
}

// ---------- grouped GEMM: 256x256 tile, 8 waves, 32x32x16 MFMA, counted vmcnt ----------
// Per part p: y[p][b][o] = bf16( sum_d xp[p][b][d] * wp[p][o][d] )   (NO gelu here)
// Triple-buffered LDS; steady-state wait = vmcnt(4), never 0 until the tail.
// LDS rows are 64B (4 chunks of 16B); swizzle involution: chunk ^= (row>>1)&3,
// applied to the GLOBAL source (linear LDS dest, rule 21) and to ds_read.
// Quarter-wave bank quads: (row*4 + perm)%8 = 0,4,1,5,2,6,3,7 -> 2 lanes/bank.
__global__ __launch_bounds__(512, 2) void gemm8_kernel(const bf16* __restrict__ xp,
                                                       const bf16* __restrict__ wp,
                                                       bf16* __restrict__ y) {
    __shared__ bf16 As[3][256 * BKT];
    __shared__ bf16 Bs[3][256 * BKT];
    const int i = blockIdx.x;
    const int p    = ((i & 7) << 1) | ((i >> 3) & 1);   // part -> XCD i&7
    const int tile = i >> 4;                             // 0..15
    const int bt = (tile >> 2) * 256;
    const int ot = (tile & 3) * 256;
    const bf16* A  = xp + (size_t)p * NB * ND;   // [B][D]
    const bf16* Bm = wp + (size_t)p * ND * ND;   // [O][D]
    const int t = threadIdx.x;
    const int l = t & 63, w = t >> 6;            // 8 waves
    const int wr = w >> 2, wc = w & 3;           // 2(M) x 4(N): wave tile 128x64
    const int lr32 = l & 31, g2 = l >> 5;        // mfma row / k-half

    f32x16 acc[4][2] = {};                       // 4 m-tiles x 2 n-tiles of 32x32

    auto stage = [&](int buf, int kt, int q) {
        const int s   = ((q & 1) * 8 + w) * 64 + l;     // 16B slot 0..1023
        const int row = s >> 2;                          // 0..255
        const int cb  = (s & 3) ^ ((row >> 1) & 3);      // inverse-swizzled chunk
        const bf16* gsrc = (q < 2 ? A + (size_t)(bt + row) * ND
                                  : Bm + (size_t)(ot + row) * ND) + kt * BKT + cb * 8;
        bf16* ldst = (q < 2 ? &As[buf][((q & 1) * 8 + w) * 512]
                            : &Bs[buf][((q & 1) * 8 + w) * 512]);
        __builtin_amdgcn_global_load_lds((const __attribute__((address_space(1))) void*)gsrc,
                                         (__attribute__((address_space(3))) void*)ldst, 16, 0, 0);
    };
    // A operand of mfma_32x32x16: row = l&31, k = (l>>5)*8 + e; K-tile has 2 k-steps.
    auto readA = [&](int buf, int m, int s) -> bf16x8 {
        const int row  = wr * 128 + m * 32 + lr32;
        const int ch   = s * 2 + g2;
        const int slot = row * 4 + (ch ^ ((row >> 1) & 3));
        return *reinterpret_cast<const bf16x8*>(&As[buf][slot * 8]);
    };
    auto readB = [&](int buf, int n, int s) -> bf16x8 {
        const int row  = wc * 64 + n * 32 + lr32;
        const int ch   = s * 2 + g2;
        const int slot = row * 4 + (ch ^ ((row >> 1) & 3));
        return *reinterpret_cast<const bf16x8*>(&Bs[buf][slot * 8]);
    };

#pragma unroll
    for (int q = 0; q < 4; ++q) stage(0, 0, q);
#pragma unroll
    for (int q = 0; q < 4; ++q) stage(1, 1, q);
    asm volatile("s_waitcnt vmcnt(4)" ::: "memory");
    __builtin_amdgcn_s_barrier();
    __builtin_amdgcn_sched_barrier(0);

    int bufc = 0, bufs = 2;
#pragma unroll 1
    for (int kt = 0; kt < NKT; ++kt) {
        // ---- phase 0: k-step 0 frags ; stage A of tile kt+2 ----
        bf16x8 bfr[2], af[4];
#pragma unroll
        for (int n = 0; n < 2; ++n) bfr[n] = readB(bufc, n, 0);
#pragma unroll
        for (int m = 0; m < 4; ++m) af[m] = readA(bufc, m, 0);
        if (kt + 2 < NKT) { stage(bufs, kt + 2, 0); stage(bufs, kt + 2, 1); }
        __builtin_amdgcn_s_barrier();
        asm volatile("s_waitcnt lgkmcnt(0)" ::: "memory");
        __builtin_amdgcn_s_setprio(1);
#pragma unroll
        for (int m = 0; m < 4; ++m)
#pragma unroll
            for (int n = 0; n < 2; ++n)
                acc[m][n] = __builtin_amdgcn_mfma_f32_32x32x16_bf16(af[m], bfr[n], acc[m][n], 0, 0, 0);
        __builtin_amdgcn_s_setprio(0);
        __builtin_amdgcn_s_barrier();
        // ---- phase 1: k-step 1 frags ; stage B of tile kt+2 ----
#pragma unroll
        for (int n = 0; n < 2; ++n) bfr[n] = readB(bufc, n, 1);
#pragma unroll
        for (int m = 0; m < 4; ++m) af[m] = readA(bufc, m, 1);
        if (kt + 2 < NKT) { stage(bufs, kt + 2, 2); stage(bufs, kt + 2, 3); }
        __builtin_amdgcn_s_barrier();
        asm volatile("s_waitcnt lgkmcnt(0)" ::: "memory");
        __builtin_amdgcn_s_setprio(1);
#pragma unroll
        for (int m = 0; m < 4; ++m)
#pragma unroll
            for (int n = 0; n < 2; ++n)
                acc[m][n] = __builtin_amdgcn_mfma_f32_32x32x16_bf16(af[m], bfr[n], acc[m][n], 0, 0, 0);
        __builtin_amdgcn_s_setprio(0);
        if (kt < NKT - 1) {
            if (kt + 2 < NKT) asm volatile("s_waitcnt vmcnt(4)" ::: "memory");
            else              asm volatile("s_waitcnt vmcnt(0)" ::: "memory");
            __builtin_amdgcn_s_barrier();
            __builtin_amdgcn_sched_barrier(0);
        }
        bufc = (bufc == 2) ? 0 : bufc + 1;
        bufs = (bufs == 2) ? 0 : bufs + 1;
    }

    // epilogue: 32x32 C/D layout col = l&31, row = (reg&3) + 8*(reg>>2) + 4*(l>>5)
    bf16* yp = y + (size_t)p * NB * ND;
#pragma unroll
    for (int m = 0; m < 4; ++m) {
#pragma unroll
        for (int n = 0; n < 2; ++n) {
#pragma unroll
            for (int reg = 0; reg < 16; ++reg) {
                const int row = bt + wr * 128 + m * 32 + (reg & 3) + 8 * (reg >> 2) + 4 * g2;
                const int col = ot + wc * 64 + n * 32 + lr32;
                yp[(size_t)row * ND + col] = __float2bfloat16(acc[m][n][reg]);
            }
        }
    }
}

// ---------- y [P][B][O] bf16 (raw) -> out [B][O][P] f32 with exact GELU ----------
__global__ __launch_bounds__(256) void unpack_kernel(const bf16* __restrict__ y,
                                                     float* __restrict__ out) {
    const size_t gidx = (size_t)blockIdx.x * 256 + threadIdx.x;  // (b,o) index
    const size_t o = gidx & 1023;
    const size_t b = gidx >> 10;
    const bf16* yb = y + b * (size_t)ND + o;
    float v[16];
#pragma unroll
    for (int p = 0; p < 16; ++p)
        v[p] = gelu_exact(__bfloat162float(yb[(size_t)p * (NB * ND)]));
    float4* dst = reinterpret_cast<float4*>(out + gidx * NP);
#pragma unroll
    for (int q = 0; q < 4; ++q)
        dst[q] = make_float4(v[q * 4], v[q * 4 + 1], v[q * 4 + 2], v[q * 4 + 3]);
}

// ---------- fallback A: 128^2 m97-style GEMM, direct strided f32 store ----------
__global__ __launch_bounds__(256, 4) void gemm_direct_kernel(const bf16* __restrict__ xp,
                                                             const bf16* __restrict__ wp,
                                                             float* __restrict__ out) {
    constexpr int BK = 32;
    __shared__ bf16 As[2][128 * BK];
    __shared__ bf16 Bs[2][128 * BK];
    const int i = blockIdx.x;
    const int p    = ((i & 7) << 1) | ((i >> 9) & 1);
    const int tile = (i >> 3) & 63;
    const int ot = (tile & 7) * 128;
    const int bt = (tile >> 3) * 128;
    const bf16* A  = xp + (size_t)p * NB * ND;
    const bf16* Bm = wp + (size_t)p * ND * ND;
    const int t = threadIdx.x;
    const int l = t & 63;
    const int w = t >> 6;
    const int wr = w >> 1, wc = w & 1;
    f32x4 acc[4][4] = {};
    auto stage = [&](int buf, int k0) {
#pragma unroll
        for (int r = 0; r < 2; ++r) {
            const int c   = r * 256 + t;
            const int row = c >> 2;
            const int cc  = c & 3;
            const bf16* ga = A  + (size_t)(bt + row) * ND + (k0 + cc * 8);
            const bf16* gb = Bm + (size_t)(ot + row) * ND + (k0 + cc * 8);
            bf16* la = &As[buf][(r * 256 + w * 64) * 8];
            bf16* lb = &Bs[buf][(r * 256 + w * 64) * 8];
            __builtin_amdgcn_global_load_lds((const __attribute__((address_space(1))) void*)ga,
                                             (__attribute__((address_space(3))) void*)la, 16, 0, 0);
            __builtin_amdgcn_global_load_lds((const __attribute__((address_space(1))) void*)gb,
                                             (__attribute__((address_space(3))) void*)lb, 16, 0, 0);
        }
    };
    int buf = 0;
    stage(0, 0);
    for (int kt = 0; kt < ND / BK; ++kt) {
        __syncthreads();
        if (kt + 1 < ND / BK) stage(buf ^ 1, (kt + 1) * BK);
        const int lr = l & 15;
        const int lk = (l >> 4) * 8;
        bf16x8 af[4], bfr[4];
#pragma unroll
        for (int m = 0; m < 4; ++m)
            af[m] = *reinterpret_cast<const bf16x8*>(&As[buf][(wr * 64 + m * 16 + lr) * BK + lk]);
#pragma unroll
        for (int n = 0; n < 4; ++n)
            bfr[n] = *reinterpret_cast<const bf16x8*>(&Bs[buf][(wc * 64 + n * 16 + lr) * BK + lk]);
#pragma unroll
        for (int m = 0; m < 4; ++m)
#pragma unroll
            for (int n = 0; n < 4; ++n)
                acc[m][n] = __builtin_amdgcn_mfma_f32_16x16x32_bf16(af[m], bfr[n], acc[m][n], 0, 0, 0);
        buf ^= 1;
    }
    const int lr4 = (l >> 4) * 4;
    const int lc  = l & 15;
    const int row0 = bt + wr * 64, col0 = ot + wc * 64;
#pragma unroll
    for (int m = 0; m < 4; ++m)
#pragma unroll
        for (int j = 0; j < 4; ++j) {
            const int r = row0 + m * 16 + lr4 + j;
#pragma unroll
            for (int n = 0; n < 4; ++n) {
                const int c = col0 + n * 16 + lc;
                out[((size_t)r * ND + c) * NP + p] = gelu_exact(acc[m][n][j]);
            }
        }
}

// ---------- fallback B: pure-f32 tiled GEMM (tiny ws) ----------
__global__ __launch_bounds__(256) void fallback_kernel(const float* __restrict__ x,
                                                       const float* __restrict__ w,
                                                       float* __restrict__ out) {
    __shared__ float As[64][17];
    __shared__ float Bs[64][17];
    const int p = blockIdx.z, bt = blockIdx.y * 64, ot = blockIdx.x * 64;
    const int t = threadIdx.x;
    const int tx = t & 15, ty = t >> 4;
    float acc[4][4] = {};
    for (int k0 = 0; k0 < ND; k0 += 16) {
        __syncthreads();
#pragma unroll
        for (int i = 0; i < 4; ++i) {
            const int idx = i * 256 + t;
            const int r = idx >> 4, k = idx & 15;
            As[r][k] = x[((size_t)(bt + r) * ND + k0 + k) * NP + p];
            Bs[r][k] = w[(size_t)p * ND * ND + (size_t)(ot + r) * ND + k0 + k];
        }
        __syncthreads();
#pragma unroll
        for (int k = 0; k < 16; ++k) {
            float a[4], bb[4];
#pragma unroll
            for (int i = 0; i < 4; ++i) a[i] = As[ty * 4 + i][k];
#pragma unroll
            for (int j = 0; j < 4; ++j) bb[j] = Bs[tx * 4 + j][k];
#pragma unroll
            for (int i = 0; i < 4; ++i)
#pragma unroll
                for (int j = 0; j < 4; ++j) acc[i][j] += a[i] * bb[j];
        }
    }
#pragma unroll
    for (int i = 0; i < 4; ++i)
#pragma unroll
        for (int j = 0; j < 4; ++j)
            out[((size_t)(bt + ty * 4 + i) * ND + (ot + tx * 4 + j)) * NP + p] =
                gelu_exact(acc[i][j]);
}

extern "C" void kernel_launch(void* const* d_in, const int* in_sizes, int n_in,
                              void* d_out, int out_size, void* d_ws, size_t ws_size,
                              hipStream_t stream) {
    const float* x = (const float*)d_in[0];
    const float* w = (const float*)d_in[1];
    float* out = (float*)d_out;

    const size_t nElem     = (size_t)NP * NB * ND;            // 16M
    const size_t packBytes = nElem * sizeof(bf16) * 2;        // 64 MiB (xp + wp)
    const size_t yBytes    = nElem * sizeof(bf16);            // 32 MiB (bf16 y)

    if (ws_size >= packBytes) {
        bf16* xp = (bf16*)d_ws;
        bf16* wp = xp + nElem;
        pack_kernel<<<NB + (int)(nElem / (256 * 8)), 256, 0, stream>>>(x, w, xp, wp);
        if (ws_size >= packBytes + yBytes) {
            bf16* y = (bf16*)((char*)d_ws + packBytes);
            gemm8_kernel<<<256, 512, 0, stream>>>(xp, wp, y);
            unpack_kernel<<<(int)(NB * ND / 256), 256, 0, stream>>>(y, out);
        } else {
            gemm_direct_kernel<<<1024, 256, 0, stream>>>(xp, wp, out);
        }
    } else {
        fallback_kernel<<<dim3(16, 16, 16), 256, 0, stream>>>(x, w, out);
    }
}